// Round 6
// baseline (554.488 us; speedup 1.0000x reference)
//
#include <hip/hip_runtime.h>
#include <hip/hip_bf16.h>

#define NUM_USERS 100000
#define NUM_ITEMS 50000
#define EMBED_DIM 64
#define N_NODES   150000                 // NUM_USERS + NUM_ITEMS
#define ROW_SHIFT 10                     // 1024 rows per bucket
#define ROWS_PER_BUCKET 1024
#define B_BUCKETS ((N_NODES + ROWS_PER_BUCKET - 1) / ROWS_PER_BUCKET)   // 147
#define BIN_CHUNK 2048                   // edges per k_bin block (8/thread)
#define COL_MASK 0x3FFFF                 // 18 bits for col (N_NODES < 262144)

typedef unsigned short ushort_t;

__device__ __forceinline__ float bf16_to_f32(ushort_t u) {
    return __uint_as_float(((unsigned)u) << 16);
}
__device__ __forceinline__ ushort_t f32_to_bf16(float f) {
    return __builtin_bit_cast(ushort_t, __float2bfloat16(f));   // RNE
}

// ---------------------------------------------------------------------------
// Pass 0: coarse bucket histogram (147 counters) via per-block LDS hist.
// ---------------------------------------------------------------------------
__global__ void k_bucket_hist(const int* __restrict__ rows, int* __restrict__ bhist, int nnz) {
    __shared__ int lh[256];
    int t = threadIdx.x;
    lh[t] = 0;
    __syncthreads();
    int base = blockIdx.x * (256 * 32);
#pragma unroll
    for (int k = 0; k < 32; k++) {
        int idx = base + k * 256 + t;
        if (idx < nnz) atomicAdd(&lh[rows[idx] >> ROW_SHIFT], 1);
    }
    __syncthreads();
    if (t < B_BUCKETS && lh[t] > 0) atomicAdd(&bhist[t], lh[t]);
}

// Pass 0b: single-block scan of bucket counts -> bucket_off, cursors, sentinel.
__global__ void k_bucket_scan(const int* __restrict__ bhist, int* __restrict__ bucket_off,
                              int* __restrict__ bucket_cursor, int* __restrict__ offs, int nnz) {
    __shared__ int lds[256];
    int t = threadIdx.x;
    int v = (t < B_BUCKETS) ? bhist[t] : 0;
    lds[t] = v;
    __syncthreads();
    for (int d = 1; d < 256; d <<= 1) {
        int y = (t >= d) ? lds[t - d] : 0;
        __syncthreads();
        lds[t] += y;
        __syncthreads();
    }
    int excl = lds[t] - v;
    if (t < B_BUCKETS) {
        bucket_off[t] = excl;
        bucket_cursor[t] = excl;
    }
    if (t == 0) {
        bucket_off[B_BUCKETS] = nnz;
        offs[N_NODES] = nnz;
    }
}

// ---------------------------------------------------------------------------
// Pass 1: LDS-binned staging, packed int2 {col | lrow<<18, val} + uint8 bucket.
// ---------------------------------------------------------------------------
__global__ void __launch_bounds__(256) k_bin(const int* __restrict__ rows,
                                             const int* __restrict__ cols,
                                             const float* __restrict__ vals,
                                             int* __restrict__ bucket_cursor,
                                             int2* __restrict__ staging, int nnz) {
    __shared__ int  ccnt[256];
    __shared__ int  cpos[256];
    __shared__ int  gdst[256];
    __shared__ int2 entries[BIN_CHUNK];            // 16 KB
    __shared__ unsigned char ebuck[BIN_CHUNK];     // 2 KB

    int t = threadIdx.x;
    int base = blockIdx.x * BIN_CHUNK;
    ccnt[t] = 0;
    __syncthreads();

    int myrow[BIN_CHUNK / 256];
#pragma unroll
    for (int k = 0; k < BIN_CHUNK / 256; k++) {
        int idx = base + k * 256 + t;
        int r = (idx < nnz) ? rows[idx] : -1;
        myrow[k] = r;
        if (r >= 0) atomicAdd(&ccnt[r >> ROW_SHIFT], 1);
    }
    __syncthreads();

    int c = ccnt[t];
    cpos[t] = c;
    __syncthreads();
    for (int d = 1; d < 256; d <<= 1) {
        int y = (t >= d) ? cpos[t - d] : 0;
        __syncthreads();
        cpos[t] += y;
        __syncthreads();
    }
    int total = cpos[255];
    int excl = cpos[t] - c;
    __syncthreads();
    cpos[t] = excl;
    __syncthreads();

#pragma unroll
    for (int k = 0; k < BIN_CHUNK / 256; k++) {
        int r = myrow[k];
        if (r >= 0) {
            int idx = base + k * 256 + t;
            int b = r >> ROW_SHIFT;
            int lrow = r & (ROWS_PER_BUCKET - 1);
            int slot = atomicAdd(&cpos[b], 1);
            entries[slot] = make_int2(cols[idx] | (lrow << 18), __float_as_int(vals[idx]));
            ebuck[slot] = (unsigned char)b;
        }
    }
    __syncthreads();

    if (t < B_BUCKETS && ccnt[t] > 0) {
        int g = atomicAdd(&bucket_cursor[t], ccnt[t]);
        gdst[t] = g - (cpos[t] - ccnt[t]);
    }
    __syncthreads();

    for (int i = t; i < total; i += 256) {
        staging[gdst[ebuck[i]] + i] = entries[i];
    }
}

// ---------------------------------------------------------------------------
// Pass 2: one block owns one bucket (1024 rows). Count -> scan -> scatter.
// ---------------------------------------------------------------------------
__global__ void __launch_bounds__(1024) k_scatter2(const int2* __restrict__ staging,
                                                   const int* __restrict__ bucket_off,
                                                   int* __restrict__ offs,
                                                   int2* __restrict__ cv) {
    __shared__ int rc[ROWS_PER_BUCKET];
    int b = blockIdx.x;
    int t = threadIdx.x;
    int beg = bucket_off[b], end = bucket_off[b + 1];
    int row0 = b << ROW_SHIFT;

    rc[t] = 0;
    __syncthreads();
    for (int i = beg + t; i < end; i += 1024)
        atomicAdd(&rc[staging[i].x >> 18], 1);
    __syncthreads();

    int c = rc[t];
    for (int d = 1; d < 1024; d <<= 1) {
        int y = (t >= d) ? rc[t - d] : 0;
        __syncthreads();
        rc[t] += y;
        __syncthreads();
    }
    int excl = rc[t] - c;
    int row = row0 + t;
    if (row < N_NODES) offs[row] = beg + excl;
    __syncthreads();
    rc[t] = excl;
    __syncthreads();

    for (int i = beg + t; i < end; i += 1024) {
        int2 e = staging[i];
        int pos = beg + atomicAdd(&rc[e.x >> 18], 1);
        cv[pos] = make_int2(e.x & COL_MASK, e.y);
    }
}

// ---------------------------------------------------------------------------
// Convert the fp32 ego table (user_emb ++ item_emb) to one bf16 table.
// ---------------------------------------------------------------------------
__global__ void k_convert(const float* __restrict__ ue, const float* __restrict__ ie,
                          ushort_t* __restrict__ xb) {
    int i = blockIdx.x * blockDim.x + threadIdx.x;   // float4 index
    const int n4 = (N_NODES * EMBED_DIM) / 4;
    if (i >= n4) return;
    const int usplit = (NUM_USERS * EMBED_DIM) / 4;
    float4 f = (i < usplit) ? ((const float4*)ue)[i] : ((const float4*)ie)[i - usplit];
    ushort4 o;
    o.x = f32_to_bf16(f.x);
    o.y = f32_to_bf16(f.y);
    o.z = f32_to_bf16(f.z);
    o.w = f32_to_bf16(f.w);
    ((ushort4*)xb)[i] = o;
}

// ---------------------------------------------------------------------------
// SpMM row body (bf16 x): one wave per row, lane = dim. Edge stream is
// wave-uniform (scalarized -> s_load). 2-deep ping-pong pipeline of 16-edge
// groups: up to 32 gathers in flight per wave (the avg row is 32 edges, so
// most rows have every gather issued before the first consume).
// ---------------------------------------------------------------------------
__device__ __forceinline__ float spmm_row(int beg, int end, int lane,
                                          const int2* __restrict__ cv,
                                          const ushort_t* __restrict__ xb) {
    float acc = 0.f;
    int e = beg;
    int n16 = (end - beg) >> 4;

    if (n16 > 0) {
        float    v0[16], v1[16];
        ushort_t r0[16], r1[16];
        // group 0 -> buf0
#pragma unroll
        for (int j = 0; j < 16; j++) {
            int2 c = cv[e + j];
            int col = __builtin_amdgcn_readfirstlane(c.x);
            v0[j] = __int_as_float(__builtin_amdgcn_readfirstlane(c.y));
            r0[j] = xb[(size_t)col * EMBED_DIM + lane];
        }
        e += 16;
        int g = 1;
#pragma unroll 1
        for (; g + 1 < n16; g += 2) {
#pragma unroll
            for (int j = 0; j < 16; j++) {          // issue -> buf1
                int2 c = cv[e + j];
                int col = __builtin_amdgcn_readfirstlane(c.x);
                v1[j] = __int_as_float(__builtin_amdgcn_readfirstlane(c.y));
                r1[j] = xb[(size_t)col * EMBED_DIM + lane];
            }
            e += 16;
#pragma unroll
            for (int j = 0; j < 16; j++) acc += v0[j] * bf16_to_f32(r0[j]);   // consume buf0
#pragma unroll
            for (int j = 0; j < 16; j++) {          // issue -> buf0
                int2 c = cv[e + j];
                int col = __builtin_amdgcn_readfirstlane(c.x);
                v0[j] = __int_as_float(__builtin_amdgcn_readfirstlane(c.y));
                r0[j] = xb[(size_t)col * EMBED_DIM + lane];
            }
            e += 16;
#pragma unroll
            for (int j = 0; j < 16; j++) acc += v1[j] * bf16_to_f32(r1[j]);   // consume buf1
        }
        if (g < n16) {
            // one leftover group: issue buf1, then consume buf0, buf1
#pragma unroll
            for (int j = 0; j < 16; j++) {
                int2 c = cv[e + j];
                int col = __builtin_amdgcn_readfirstlane(c.x);
                v1[j] = __int_as_float(__builtin_amdgcn_readfirstlane(c.y));
                r1[j] = xb[(size_t)col * EMBED_DIM + lane];
            }
            e += 16;
#pragma unroll
            for (int j = 0; j < 16; j++) acc += v0[j] * bf16_to_f32(r0[j]);
#pragma unroll
            for (int j = 0; j < 16; j++) acc += v1[j] * bf16_to_f32(r1[j]);
        } else {
#pragma unroll
            for (int j = 0; j < 16; j++) acc += v0[j] * bf16_to_f32(r0[j]);
        }
    }
    // single 8-edge group
    if (e + 8 <= end) {
        float    v[8];
        ushort_t r[8];
#pragma unroll
        for (int j = 0; j < 8; j++) {
            int2 c = cv[e + j];
            int col = __builtin_amdgcn_readfirstlane(c.x);
            v[j] = __int_as_float(__builtin_amdgcn_readfirstlane(c.y));
            r[j] = xb[(size_t)col * EMBED_DIM + lane];
        }
        e += 8;
#pragma unroll
        for (int j = 0; j < 8; j++) acc += v[j] * bf16_to_f32(r[j]);
    }
    // scalar tail
#pragma unroll 1
    for (; e < end; e++) {
        int2 c = cv[e];
        int col = __builtin_amdgcn_readfirstlane(c.x);
        float v = __int_as_float(__builtin_amdgcn_readfirstlane(c.y));
        acc += v * bf16_to_f32(xb[(size_t)col * EMBED_DIM + lane]);
    }
    return acc;
}

__global__ void k_spmm(const int* __restrict__ offs, const int2* __restrict__ cv,
                       const ushort_t* __restrict__ xb, ushort_t* __restrict__ out) {
    int row = (blockIdx.x * blockDim.x + threadIdx.x) >> 6;
    int lane = threadIdx.x & 63;
    if (row >= N_NODES) return;
    row = __builtin_amdgcn_readfirstlane(row);
    int beg = __builtin_amdgcn_readfirstlane(offs[row]);
    int end = __builtin_amdgcn_readfirstlane(offs[row + 1]);
    float acc = spmm_row(beg, end, lane, cv, xb);
    out[(size_t)row * EMBED_DIM + lane] = f32_to_bf16(acc);
}

// Last layer: only batch rows are consumed — compute just those, accumulate fp32.
__global__ void k_spmm_batch(const int* __restrict__ offs, const int2* __restrict__ cv,
                             const ushort_t* __restrict__ xb,
                             const int* __restrict__ users, const int* __restrict__ items,
                             float* __restrict__ u_acc, float* __restrict__ i_acc,
                             int batch) {
    int w = (blockIdx.x * blockDim.x + threadIdx.x) >> 6;
    int lane = threadIdx.x & 63;
    if (w >= 2 * batch) return;
    int b, row;
    float* dst;
    if (w < batch) { b = w;         row = users[b];             dst = u_acc; }
    else           { b = w - batch; row = NUM_USERS + items[b]; dst = i_acc; }
    row = __builtin_amdgcn_readfirstlane(row);
    int beg = __builtin_amdgcn_readfirstlane(offs[row]);
    int end = __builtin_amdgcn_readfirstlane(offs[row + 1]);
    float acc = spmm_row(beg, end, lane, cv, xb);
    dst[(size_t)b * EMBED_DIM + lane] += acc;
}

// ---------------------------------------------------------------------------
__global__ void k_gather_f32(const int* __restrict__ users, const int* __restrict__ items,
                             const float* __restrict__ ue, const float* __restrict__ ie,
                             float* __restrict__ u_acc, float* __restrict__ i_acc, int batch) {
    int w = (blockIdx.x * blockDim.x + threadIdx.x) >> 6;
    int lane = threadIdx.x & 63;
    if (w >= batch) return;
    int nu = users[w];
    int ni = items[w];
    size_t o = (size_t)w * EMBED_DIM + lane;
    u_acc[o] = ue[(size_t)nu * EMBED_DIM + lane];
    i_acc[o] = ie[(size_t)ni * EMBED_DIM + lane];
}

__global__ void k_gather_bf16(const int* __restrict__ users, const int* __restrict__ items,
                              const ushort_t* __restrict__ xb,
                              float* __restrict__ u_acc, float* __restrict__ i_acc, int batch) {
    int w = (blockIdx.x * blockDim.x + threadIdx.x) >> 6;
    int lane = threadIdx.x & 63;
    if (w >= batch) return;
    int nu = users[w];
    int ni = NUM_USERS + items[w];
    size_t o = (size_t)w * EMBED_DIM + lane;
    u_acc[o] += bf16_to_f32(xb[(size_t)nu * EMBED_DIM + lane]);
    i_acc[o] += bf16_to_f32(xb[(size_t)ni * EMBED_DIM + lane]);
}

__global__ void k_dot(const float* __restrict__ u_acc, const float* __restrict__ i_acc,
                      float* __restrict__ out, int batch) {
    int w = (blockIdx.x * blockDim.x + threadIdx.x) >> 6;
    int lane = threadIdx.x & 63;
    if (w >= batch) return;
    size_t o = (size_t)w * EMBED_DIM + lane;
    float p = u_acc[o] * i_acc[o];
#pragma unroll
    for (int d = 32; d > 0; d >>= 1) p += __shfl_down(p, d, 64);
    if (lane == 0) out[w] = p * (1.0f / 16.0f);
}

// ---------------------------------------------------------------------------

extern "C" void kernel_launch(void* const* d_in, const int* in_sizes, int n_in,
                              void* d_out, int out_size, void* d_ws, size_t ws_size,
                              hipStream_t stream) {
    const int*   users    = (const int*)  d_in[0];
    const int*   items    = (const int*)  d_in[1];
    const int*   adj_rows = (const int*)  d_in[2];
    const int*   adj_cols = (const int*)  d_in[3];
    const float* adj_vals = (const float*)d_in[4];
    const float* user_emb = (const float*)d_in[5];
    const float* item_emb = (const float*)d_in[6];
    float* out = (float*)d_out;

    const int batch = in_sizes[0];
    const int nnz   = in_sizes[2];

    char* p = (char*)d_ws;
    auto alloc = [&](size_t bytes) -> char* {
        char* r = p;
        p += (bytes + 255) & ~(size_t)255;
        return r;
    };
    const size_t xb_bytes = (size_t)N_NODES * EMBED_DIM * 2;       // 19.2 MB
    int*      offs          = (int*)  alloc(((size_t)N_NODES + 1) * 4);
    int*      bhist         = (int*)  alloc(256 * 4);
    int*      bucket_off    = (int*)  alloc(256 * 4);
    int*      bucket_cursor = (int*)  alloc(256 * 4);
    int2*     cv            = (int2*) alloc((size_t)nnz * 8);      // final CSR (col,val)
    // region overlays: int2 staging (build phase) vs xbA+xbB (layer buffers)
    size_t    region_bytes  = (size_t)nnz * 8;
    if (region_bytes < 2 * xb_bytes) region_bytes = 2 * xb_bytes;
    char*     region        = alloc(region_bytes);
    int2*     staging       = (int2*)region;
    ushort_t* xbA           = (ushort_t*)region;
    ushort_t* xbB           = (ushort_t*)(region + xb_bytes);
    ushort_t* xb_ego        = (ushort_t*)alloc(xb_bytes);
    float*    u_acc         = (float*)alloc((size_t)batch * EMBED_DIM * 4);
    float*    i_acc         = (float*)alloc((size_t)batch * EMBED_DIM * 4);

    const int g_bhist  = (nnz + 256 * 32 - 1) / (256 * 32);
    const int g_bin    = (nnz + BIN_CHUNK - 1) / BIN_CHUNK;
    const int g_conv   = ((N_NODES * EMBED_DIM / 4) + 255) / 256;
    const int g_nodes  = (N_NODES + 3) / 4;          // 4 rows (waves) / 256-thr block
    const int g_batch  = (batch + 3) / 4;
    const int g_batch2 = (2 * batch + 3) / 4;

    // ---- CSR build (bucket-staged counting sort) ----
    hipMemsetAsync(bhist, 0, 256 * 4, stream);
    k_bucket_hist<<<g_bhist, 256, 0, stream>>>(adj_rows, bhist, nnz);
    k_bucket_scan<<<1, 256, 0, stream>>>(bhist, bucket_off, bucket_cursor, offs, nnz);
    k_bin<<<g_bin, 256, 0, stream>>>(adj_rows, adj_cols, adj_vals, bucket_cursor, staging, nnz);
    k_scatter2<<<B_BUCKETS, 1024, 0, stream>>>(staging, bucket_off, offs, cv);

    // ---- bf16 ego table ----
    k_convert<<<g_conv, 256, 0, stream>>>(user_emb, item_emb, xb_ego);

    // ---- layer 0 (ego, exact fp32) ----
    k_gather_f32<<<g_batch, 256, 0, stream>>>(users, items, user_emb, item_emb,
                                              u_acc, i_acc, batch);

    // ---- layer 1: xbA = A * ego ----
    k_spmm<<<g_nodes, 256, 0, stream>>>(offs, cv, xb_ego, xbA);
    k_gather_bf16<<<g_batch, 256, 0, stream>>>(users, items, xbA, u_acc, i_acc, batch);

    // ---- layer 2: xbB = A * xbA ----
    k_spmm<<<g_nodes, 256, 0, stream>>>(offs, cv, xbA, xbB);
    k_gather_bf16<<<g_batch, 256, 0, stream>>>(users, items, xbB, u_acc, i_acc, batch);

    // ---- layer 3: only batch rows needed — fused spmm+gather (fp32 acc) ----
    k_spmm_batch<<<g_batch2, 256, 0, stream>>>(offs, cv, xbB, users, items,
                                               u_acc, i_acc, batch);

    // ---- final dot ----
    k_dot<<<g_batch, 256, 0, stream>>>(u_acc, i_acc, out, batch);
}